// Round 4
// baseline (1731.476 us; speedup 1.0000x reference)
//
#include <hip/hip_runtime.h>

typedef __attribute__((ext_vector_type(8))) short short8;   // 8 x bf16
typedef __attribute__((ext_vector_type(4))) float f32x4;

__device__ __forceinline__ float lrelu_f(float v) { return v > 0.f ? v : 0.01f * v; }
__device__ __forceinline__ short f2bf(float f) {
    unsigned u = __float_as_uint(f);
    return (short)((u + 0x7FFFu + ((u >> 16) & 1u)) >> 16);    // RNE
}
__device__ __forceinline__ float bf2f(unsigned short h) {
    return __uint_as_float(((unsigned)h) << 16);
}

// converts + count zeroing in one launch
__global__ __launch_bounds__(256) void prep(
    const float* __restrict__ x,  short* __restrict__ xb,  int nx,
    const float* __restrict__ W1, short* __restrict__ W1b, int n1,
    const float* __restrict__ W12,short* __restrict__ W12b,int n12,
    const float* __restrict__ W2, short* __restrict__ W2b, int n2,
    const float* __restrict__ W3, short* __restrict__ W3b, int n3,
    const float* __restrict__ Wp, short* __restrict__ Wpb, int np,
    int* __restrict__ Ca, int na, int* __restrict__ Cb, int nb,
    int* __restrict__ Cp, int nc)
{
    const int total = nx + n1 + n12 + n2 + n3 + np + na + nb + nc;
    for (int i = blockIdx.x * 256 + threadIdx.x; i < total; i += gridDim.x * 256) {
        int j = i;
        if (j < nx)  { xb[j]   = f2bf(x[j]);   continue; } j -= nx;
        if (j < n1)  { W1b[j]  = f2bf(W1[j]);  continue; } j -= n1;
        if (j < n12) { W12b[j] = f2bf(W12[j]); continue; } j -= n12;
        if (j < n2)  { W2b[j]  = f2bf(W2[j]);  continue; } j -= n2;
        if (j < n3)  { W3b[j]  = f2bf(W3[j]);  continue; } j -= n3;
        if (j < np)  { Wpb[j]  = f2bf(Wp[j]);  continue; } j -= np;
        if (j < na)  { Ca[j] = 0; continue; }              j -= na;
        if (j < nb)  { Cb[j] = 0; continue; }              j -= nb;
        Cp[j] = 0;
    }
}

// all three CSR builds in one dispatch; 8 entries / thread for atomic ILP
__global__ __launch_bounds__(256) void csr_build3(
    const int* __restrict__ ia, int Ea, int* __restrict__ Ca, int* __restrict__ Sa, int capA, int BA,
    const int* __restrict__ ib, int Eb, int* __restrict__ Cb, int* __restrict__ Sb, int capB, int BB,
    const int* __restrict__ ip, int Ep, int* __restrict__ Cp, int* __restrict__ Sp, int capP)
{
    const int b = blockIdx.x;
    const int* io; int E; int* C; int* S; int cap; int lb;
    if (b < BA)           { io = ia; E = Ea; C = Ca; S = Sa; cap = capA; lb = b; }
    else if (b < BA + BB) { io = ib; E = Eb; C = Cb; S = Sb; cap = capB; lb = b - BA; }
    else                  { io = ip; E = Ep; C = Cp; S = Sp; cap = capP; lb = b - BA - BB; }
    const int e0 = lb * 2048 + threadIdx.x * 8;
    if (e0 >= E) return;
    if (e0 + 8 <= E) {
        int4 v0 = *(const int4*)(io + e0);
        int4 v1 = *(const int4*)(io + e0 + 4);
        int o[8] = {v0.x, v0.y, v0.z, v0.w, v1.x, v1.y, v1.z, v1.w};
        int p[8];
        #pragma unroll
        for (int j = 0; j < 8; ++j) p[j] = atomicAdd(&C[o[j]], 1);
        #pragma unroll
        for (int j = 0; j < 8; ++j)
            if (p[j] < cap) S[(size_t)o[j] * cap + p[j]] = e0 + j;
    } else {
        for (int e = e0; e < E && e < e0 + 8; ++e) {
            int o = io[e];
            int pos = atomicAdd(&C[o], 1);
            if (pos < cap) S[(size_t)o * cap + pos] = e;
        }
    }
}

// Phase 1: per-offset GEMM, y[e - kLo*P][64] bf16, coalesced via in-wave LDS transpose.
// Also zeroes the 128-float stats buffer (block 0) for the following reduce.
template<int CIN>
__global__ __launch_bounds__(256) void spconv_y(
    const short* __restrict__ feats,   // [N_in, CIN] bf16
    const short* __restrict__ W,       // [K, CIN, 64] bf16 (global k index)
    const int*   __restrict__ iin,
    int P, int kLo, int kHi, int tilesPerK, int wavesPerK, int TPW,
    short* __restrict__ y, float* __restrict__ zstats)
{
    if (zstats && blockIdx.x == 0 && threadIdx.x < 128) zstats[threadIdx.x] = 0.f;
    constexpr int KS = CIN / 32;
    __shared__ short lds[4][16 * 64];
    const int lane = threadIdx.x & 63;
    const int wib  = threadIdx.x >> 6;
    int wid = blockIdx.x * 4 + wib;
    wid = __builtin_amdgcn_readfirstlane(wid);
    const int k = kLo + wid / wavesPerK;
    if (k >= kHi) return;
    const int wslot = wid % wavesPerK;
    int t0 = wslot * TPW;
    if (t0 >= tilesPerK) return;
    const int t1 = (t0 + TPW < tilesPerK) ? t0 + TPW : tilesPerK;
    const int kBase = k * P, kEnd = kBase + P;
    const int col = lane & 15, g = lane >> 4;

    short8 bf[KS][4];
    const short* wk = W + (size_t)k * CIN * 64;
    #pragma unroll
    for (int kk = 0; kk < KS; ++kk)
        #pragma unroll
        for (int ct = 0; ct < 4; ++ct)
            #pragma unroll
            for (int r = 0; r < 8; ++r)
                bf[kk][ct][r] = wk[(size_t)(kk * 32 + g * 8 + r) * 64 + ct * 16 + col];

    short* my = lds[wib];
    const size_t eOff = (size_t)kLo * P;
    const int row = lane >> 2;
    const int seg = lane & 3;

    for (int t = t0; t < t1; ++t) {
        const int base = kBase + t * 16;
        int ein = base + col;
        if (ein >= kEnd) ein = kEnd - 1;
        const int rin = iin[ein];
        short8 af[KS];
        const short* fr = feats + (size_t)rin * CIN + g * 8;
        #pragma unroll
        for (int kk = 0; kk < KS; ++kk)
            af[kk] = *(const short8*)(fr + kk * 32);

        f32x4 acc[4] = {f32x4{0,0,0,0}, f32x4{0,0,0,0}, f32x4{0,0,0,0}, f32x4{0,0,0,0}};
        #pragma unroll
        for (int kk = 0; kk < KS; ++kk)
            #pragma unroll
            for (int ct = 0; ct < 4; ++ct)
                acc[ct] = __builtin_amdgcn_mfma_f32_16x16x32_bf16(af[kk], bf[kk][ct], acc[ct], 0, 0, 0);

        #pragma unroll
        for (int ct = 0; ct < 4; ++ct)
            #pragma unroll
            for (int j = 0; j < 4; ++j)
                my[(g * 4 + j) * 64 + ct * 16 + col] = f2bf(acc[ct][j]);
        short8 v0 = *(const short8*)&my[lane * 16];
        short8 v1 = *(const short8*)&my[lane * 16 + 8];
        if (base + row < kEnd) {
            short* dst = y + (size_t)(base + row - eOff) * 64 + seg * 16;
            *(short8*)dst = v0;
            *(short8*)(dst + 8) = v1;
        }
    }
}

// Phase 2: out-centric reduce; wave = R rows, lane = channel. Optionally fuses
// BN-stats accumulation (sum/sumsq of lrelu(row)) into `stats` (pre-zeroed).
__global__ __launch_bounds__(256) void reduce_rows(
    const short* __restrict__ y, const int* __restrict__ counts,
    const int* __restrict__ slots, int cap, int eLo, int eHi,
    float* __restrict__ out, int nRows, int accumulate, int R,
    float* __restrict__ stats)
{
    __shared__ float sred[2][4][64];
    const int lane = threadIdx.x & 63;
    const int wib  = threadIdx.x >> 6;
    const int w = blockIdx.x * 4 + wib;
    const unsigned short* yu = (const unsigned short*)y;
    float st_s = 0.f, st_q = 0.f;
    const int r0 = w * R;
    for (int r = r0; r < r0 + R && r < nRows; ++r) {
        int cnt = counts[r]; if (cnt > cap) cnt = cap;
        const int* sl = slots + (size_t)r * cap;
        float a0 = 0.f, a1 = 0.f, a2 = 0.f, a3 = 0.f;
        int i = 0;
        for (; i + 4 <= cnt; i += 4) {
            int e0 = sl[i], e1 = sl[i+1], e2 = sl[i+2], e3 = sl[i+3];
            if (e0 >= eLo && e0 < eHi) a0 += bf2f(yu[(size_t)(e0 - eLo) * 64 + lane]);
            if (e1 >= eLo && e1 < eHi) a1 += bf2f(yu[(size_t)(e1 - eLo) * 64 + lane]);
            if (e2 >= eLo && e2 < eHi) a2 += bf2f(yu[(size_t)(e2 - eLo) * 64 + lane]);
            if (e3 >= eLo && e3 < eHi) a3 += bf2f(yu[(size_t)(e3 - eLo) * 64 + lane]);
        }
        for (; i < cnt; ++i) {
            int e = sl[i];
            if (e >= eLo && e < eHi) a0 += bf2f(yu[(size_t)(e - eLo) * 64 + lane]);
        }
        float s = (a0 + a1) + (a2 + a3);
        float* op = out + (size_t)r * 64 + lane;
        if (accumulate) s += *op;
        *op = s;
        if (stats) { float v = lrelu_f(s); st_s += v; st_q += v * v; }
    }
    if (stats) {
        sred[0][wib][lane] = st_s; sred[1][wib][lane] = st_q;
        __syncthreads();
        if (wib == 0) {
            float ss = sred[0][0][lane] + sred[0][1][lane] + sred[0][2][lane] + sred[0][3][lane];
            float qq = sred[1][0][lane] + sred[1][1][lane] + sred[1][2][lane] + sred[1][3][lane];
            atomicAdd(&stats[lane], ss);
            atomicAdd(&stats[64 + lane], qq);
        }
    }
}

__global__ __launch_bounds__(256) void bn_apply(
    const float* __restrict__ A, const float* __restrict__ stats,
    const float* __restrict__ gamma, const float* __restrict__ beta,
    const float* __restrict__ addsrc,
    float* __restrict__ out_f32, short* __restrict__ out_bf, int n)
{
    const int c = threadIdx.x & 63;
    const float inv_n = 1.0f / (float)n;
    const float m   = stats[c] * inv_n;
    const float var = stats[64 + c] * inv_n - m * m;
    const float sc  = rsqrtf(var + 1e-5f) * gamma[c];
    const float bb  = beta[c] - m * sc;
    const long total = (long)n * 64;
    const long stride = (long)gridDim.x * blockDim.x;
    for (long i = (long)blockIdx.x * blockDim.x + threadIdx.x; i < total; i += stride) {
        float r = lrelu_f(A[i]) * sc + bb;
        if (addsrc) r += addsrc[i];
        if (out_f32) out_f32[i] = r;
        if (out_bf)  out_bf[i]  = f2bf(r);
    }
}

// ---------------- fallback (atomic path) kernels ----------------
template<int CIN>
__global__ __launch_bounds__(256) void spconv_mfma(
    const short* __restrict__ feats, const short* __restrict__ W,
    const int* __restrict__ iin, const int* __restrict__ iout,
    int P, int tilesPerK, int wavesPerK, int K, int TPW,
    float* __restrict__ out)
{
    constexpr int KS = CIN / 32;
    const int lane = threadIdx.x & 63;
    int wid = blockIdx.x * 4 + (threadIdx.x >> 6);
    wid = __builtin_amdgcn_readfirstlane(wid);
    const int k = wid / wavesPerK;
    if (k >= K) return;
    const int wslot = wid % wavesPerK;
    int t0 = wslot * TPW;
    if (t0 >= tilesPerK) return;
    const int t1 = (t0 + TPW < tilesPerK) ? t0 + TPW : tilesPerK;
    const int kBase = k * P, kEnd = kBase + P;
    const int col = lane & 15, g = lane >> 4;
    short8 bf[KS][4];
    const short* wk = W + (size_t)k * CIN * 64;
    #pragma unroll
    for (int kk = 0; kk < KS; ++kk)
        #pragma unroll
        for (int ct = 0; ct < 4; ++ct)
            #pragma unroll
            for (int r = 0; r < 8; ++r)
                bf[kk][ct][r] = wk[(size_t)(kk * 32 + g * 8 + r) * 64 + ct * 16 + col];
    for (int t = t0; t < t1; ++t) {
        const int base = kBase + t * 16;
        int ein = base + col;
        if (ein >= kEnd) ein = kEnd - 1;
        const int rin = iin[ein];
        short8 af[KS];
        const short* fr = feats + (size_t)rin * CIN + g * 8;
        #pragma unroll
        for (int kk = 0; kk < KS; ++kk)
            af[kk] = *(const short8*)(fr + kk * 32);
        f32x4 acc[4] = {f32x4{0,0,0,0}, f32x4{0,0,0,0}, f32x4{0,0,0,0}, f32x4{0,0,0,0}};
        #pragma unroll
        for (int kk = 0; kk < KS; ++kk)
            #pragma unroll
            for (int ct = 0; ct < 4; ++ct)
                acc[ct] = __builtin_amdgcn_mfma_f32_16x16x32_bf16(af[kk], bf[kk][ct], acc[ct], 0, 0, 0);
        const int rbase = base + g * 4;
        #pragma unroll
        for (int j = 0; j < 4; ++j) {
            const int er = rbase + j;
            if (er < kEnd) {
                const int rout = iout[er];
                float* op = out + (size_t)rout * 64 + col;
                #pragma unroll
                for (int ct = 0; ct < 4; ++ct)
                    atomicAdd(op + ct * 16, acc[ct][j]);
            }
        }
    }
}

__global__ __launch_bounds__(256) void bn_stats(
    const float* __restrict__ A, int n, float* __restrict__ stats)
{
    __shared__ float ls[256], lq[256];
    float s = 0.f, q = 0.f;
    const long total = (long)n * 64;
    const long stride = (long)gridDim.x * 256;
    for (long i = (long)blockIdx.x * 256 + threadIdx.x; i < total; i += stride) {
        float v = lrelu_f(A[i]);
        s += v; q += v * v;
    }
    ls[threadIdx.x] = s; lq[threadIdx.x] = q;
    __syncthreads();
    if (threadIdx.x < 64) {
        atomicAdd(&stats[threadIdx.x],
                  ls[threadIdx.x] + ls[threadIdx.x + 64] + ls[threadIdx.x + 128] + ls[threadIdx.x + 192]);
        atomicAdd(&stats[64 + threadIdx.x],
                  lq[threadIdx.x] + lq[threadIdx.x + 64] + lq[threadIdx.x + 128] + lq[threadIdx.x + 192]);
    }
}

extern "C" void kernel_launch(void* const* d_in, const int* in_sizes, int n_in,
                              void* d_out, int out_size, void* d_ws, size_t ws_size,
                              hipStream_t stream)
{
    const float* x   = (const float*)d_in[0];
    const float* W1  = (const float*)d_in[1];
    const float* W12 = (const float*)d_in[2];
    const float* W2  = (const float*)d_in[3];
    const float* W3  = (const float*)d_in[4];
    const float* Wp  = (const float*)d_in[5];
    const float* g0  = (const float*)d_in[6];
    const float* b0  = (const float*)d_in[7];
    const float* g02 = (const float*)d_in[8];
    const float* b02 = (const float*)d_in[9];
    const float* g1  = (const float*)d_in[10];
    const float* b1  = (const float*)d_in[11];
    const float* g2  = (const float*)d_in[12];
    const float* b2  = (const float*)d_in[13];
    const int* rb_a_in  = (const int*)d_in[14];
    const int* rb_a_out = (const int*)d_in[15];
    const int* rb_b_in  = (const int*)d_in[16];
    const int* rb_b_out = (const int*)d_in[17];
    const int* rb_p_in  = (const int*)d_in[18];
    const int* rb_p_out = (const int*)d_in[19];

    const int N  = in_sizes[0] / 32;
    const int M  = out_size / 64 - N;
    const int Ea = in_sizes[14];
    const int Eb = in_sizes[16];
    const int Ep = in_sizes[18];
    const int Ka = Ea / N, Kp = Ep / N;
    const int P  = N;

    float* resB = (float*)d_out;
    float* resA = resB + (size_t)M * 64;

    const int CAP_AB = 40, CAP_P = 224;

    // ---- workspace layout ----
    size_t off = 0;
    auto take = [&](size_t bytes) { size_t o = off; off += (bytes + 255) & ~(size_t)255; return o; };
    char* base = (char*)d_ws;
    size_t oA   = take((size_t)N * 64 * 4);
    size_t oB   = take((size_t)N * 64 * 4);
    size_t oxb  = take((size_t)N * 32 * 2);
    size_t otb  = take((size_t)N * 64 * 2);
    size_t oW1  = take((size_t)9 * 32 * 64 * 2);
    size_t oW12 = take((size_t)9 * 64 * 64 * 2);
    size_t oW2  = take((size_t)9 * 32 * 64 * 2);
    size_t oW3  = take((size_t)9 * 64 * 64 * 2);
    size_t oWp  = take((size_t)27 * 64 * 64 * 2);
    size_t oSt  = take(128 * 4);
    size_t oCa  = take((size_t)N * 4);
    size_t oCb  = take((size_t)N * 4);
    size_t oCp  = take((size_t)M * 4);
    size_t oSa  = take((size_t)N * CAP_AB * 4);
    size_t oSb  = take((size_t)N * CAP_AB * 4);
    size_t oSp  = take((size_t)M * CAP_P * 4);
    size_t oY   = off;                                   // y buffer is last
    const size_t needChunk = off + (((size_t)Ka * P * 64 * 2 + 255) & ~(size_t)255);
    const size_t needFull  = off + (((size_t)Kp * P * 64 * 2 + 255) & ~(size_t)255);
    const bool fitsChunk = needChunk <= ws_size;
    const bool fitsFull  = needFull  <= ws_size;

    float* A     = (float*)(base + oA);
    float* B     = (float*)(base + oB);
    short* x_bf  = (short*)(base + oxb);
    short* t_bf  = (short*)(base + otb);
    short* W1b   = (short*)(base + oW1);
    short* W12b  = (short*)(base + oW12);
    short* W2b   = (short*)(base + oW2);
    short* W3b   = (short*)(base + oW3);
    short* Wpb   = (short*)(base + oWp);
    float* stats = (float*)(base + oSt);
    int*   Ca    = (int*)(base + oCa);
    int*   Cb    = (int*)(base + oCb);
    int*   Cp    = (int*)(base + oCp);
    int*   Sa    = (int*)(base + oSa);
    int*   Sb    = (int*)(base + oSb);
    int*   Sp    = (int*)(base + oSp);
    short* yb    = (short*)(base + oY);

    dim3 blk(256);
    const int tilesPerK = (P + 15) / 16;
    const int nx = N * 32, n1 = 9*32*64, n12 = 9*64*64, n2 = 9*32*64, n3 = 9*64*64, np = 27*64*64;

    // prep: converts (+ count zeroing on CSR path)
    prep<<<2048, blk, 0, stream>>>(x, x_bf, nx, W1, W1b, n1, W12, W12b, n12,
                                   W2, W2b, n2, W3, W3b, n3, Wp, Wpb, np,
                                   fitsChunk ? Ca : nullptr, fitsChunk ? N : 0,
                                   fitsChunk ? Cb : nullptr, fitsChunk ? N : 0,
                                   fitsChunk ? Cp : nullptr, fitsChunk ? M : 0);

    if (fitsChunk) {
        const int TPW = 4;
        const int wavesPerK = (tilesPerK + TPW - 1) / TPW;
        auto gWaves = [&](int nk) { return dim3((unsigned)((nk * wavesPerK + 3) / 4)); };
        auto gRowsR = [](int nr, int R) { return dim3((unsigned)((nr + 4 * R - 1) / (4 * R))); };
        const int RS = 32;    // rows/wave for stats-fused reduces

        const int BA = (Ea + 2047) / 2048, BB = (Eb + 2047) / 2048, BP = (Ep + 2047) / 2048;
        csr_build3<<<dim3((unsigned)(BA + BB + BP)), blk, 0, stream>>>(
            rb_a_out, Ea, Ca, Sa, CAP_AB, BA,
            rb_b_out, Eb, Cb, Sb, CAP_AB, BB,
            rb_p_out, Ep, Cp, Sp, CAP_P);

        // conv1 (rb_a, 32->64) -> A ; bn -> t_bf
        spconv_y<32><<<gWaves(Ka), blk, 0, stream>>>(x_bf, W1b, rb_a_in, P, 0, Ka, tilesPerK, wavesPerK, TPW, yb, stats);
        reduce_rows<<<gRowsR(N, RS), blk, 0, stream>>>(yb, Ca, Sa, CAP_AB, 0, Ea, A, N, 0, RS, stats);
        bn_apply<<<512, blk, 0, stream>>>(A, stats, g0, b0, nullptr, nullptr, t_bf, N);

        // conv1_2 (rb_b, 64->64) -> A ; bn -> B (f32)
        spconv_y<64><<<gWaves(Ka), blk, 0, stream>>>(t_bf, W12b, rb_b_in, P, 0, Ka, tilesPerK, wavesPerK, TPW, yb, stats);
        reduce_rows<<<gRowsR(N, RS), blk, 0, stream>>>(yb, Cb, Sb, CAP_AB, 0, Eb, A, N, 0, RS, stats);
        bn_apply<<<512, blk, 0, stream>>>(A, stats, g02, b02, nullptr, B, nullptr, N);

        // conv2 (rb_b, 32->64) -> A ; bn -> t_bf
        spconv_y<32><<<gWaves(Ka), blk, 0, stream>>>(x_bf, W2b, rb_b_in, P, 0, Ka, tilesPerK, wavesPerK, TPW, yb, stats);
        reduce_rows<<<gRowsR(N, RS), blk, 0, stream>>>(yb, Cb, Sb, CAP_AB, 0, Eb, A, N, 0, RS, stats);
        bn_apply<<<512, blk, 0, stream>>>(A, stats, g1, b1, nullptr, nullptr, t_bf, N);

        // conv3 (rb_a, 64->64) -> A ; bn + shortcut -> resA (f32) + t_bf (bf16)
        spconv_y<64><<<gWaves(Ka), blk, 0, stream>>>(t_bf, W3b, rb_a_in, P, 0, Ka, tilesPerK, wavesPerK, TPW, yb, stats);
        reduce_rows<<<gRowsR(N, RS), blk, 0, stream>>>(yb, Ca, Sa, CAP_AB, 0, Ea, A, N, 0, RS, stats);
        bn_apply<<<512, blk, 0, stream>>>(A, stats, g2, b2, B, resA, t_bf, N);

        // pool conv (rb_p, 64->64) -> resB
        if (fitsFull) {
            spconv_y<64><<<gWaves(Kp), blk, 0, stream>>>(t_bf, Wpb, rb_p_in, P, 0, Kp, tilesPerK, wavesPerK, TPW, yb, nullptr);
            reduce_rows<<<gRowsR(M, 2), blk, 0, stream>>>(yb, Cp, Sp, CAP_P, 0, Ep, resB, M, 0, 2, nullptr);
        } else {
            const int kc[5] = {0, 7, 14, 21, Kp};
            for (int c = 0; c < 4; ++c) {
                const int kLo = kc[c], kHi = kc[c + 1];
                spconv_y<64><<<gWaves(kHi - kLo), blk, 0, stream>>>(t_bf, Wpb, rb_p_in, P, kLo, kHi, tilesPerK, wavesPerK, TPW, yb, nullptr);
                reduce_rows<<<gRowsR(M, 1), blk, 0, stream>>>(yb, Cp, Sp, CAP_P, kLo * P, kHi * P, resB, M, c > 0, 1, nullptr);
            }
        }
    } else {
        // -------- fallback: atomic path --------
        const int TPW = 16;
        const int wavesPerK = (tilesPerK + TPW - 1) / TPW;
        auto cblocks = [&](int K) { return dim3((unsigned)((K * wavesPerK + 3) / 4)); };
        const size_t fbytes = (size_t)N * 64 * sizeof(float);

        hipMemsetAsync(A, 0, fbytes, stream);
        spconv_mfma<32><<<cblocks(Ka), blk, 0, stream>>>(x_bf, W1b, rb_a_in, rb_a_out, P, tilesPerK, wavesPerK, Ka, TPW, A);
        hipMemsetAsync(stats, 0, 512, stream);
        bn_stats<<<256, blk, 0, stream>>>(A, N, stats);
        bn_apply<<<512, blk, 0, stream>>>(A, stats, g0, b0, nullptr, nullptr, t_bf, N);

        hipMemsetAsync(A, 0, fbytes, stream);
        spconv_mfma<64><<<cblocks(Ka), blk, 0, stream>>>(t_bf, W12b, rb_b_in, rb_b_out, P, tilesPerK, wavesPerK, Ka, TPW, A);
        hipMemsetAsync(stats, 0, 512, stream);
        bn_stats<<<256, blk, 0, stream>>>(A, N, stats);
        bn_apply<<<512, blk, 0, stream>>>(A, stats, g02, b02, nullptr, B, nullptr, N);

        hipMemsetAsync(A, 0, fbytes, stream);
        spconv_mfma<32><<<cblocks(Ka), blk, 0, stream>>>(x_bf, W2b, rb_b_in, rb_b_out, P, tilesPerK, wavesPerK, Ka, TPW, A);
        hipMemsetAsync(stats, 0, 512, stream);
        bn_stats<<<256, blk, 0, stream>>>(A, N, stats);
        bn_apply<<<512, blk, 0, stream>>>(A, stats, g1, b1, nullptr, nullptr, t_bf, N);

        hipMemsetAsync(resA, 0, fbytes, stream);
        spconv_mfma<64><<<cblocks(Ka), blk, 0, stream>>>(t_bf, W3b, rb_a_in, rb_a_out, P, tilesPerK, wavesPerK, Ka, TPW, resA);
        hipMemsetAsync(stats, 0, 512, stream);
        bn_stats<<<256, blk, 0, stream>>>(resA, N, stats);
        bn_apply<<<512, blk, 0, stream>>>(resA, stats, g2, b2, B, resA, t_bf, N);

        hipMemsetAsync(resB, 0, (size_t)M * 64 * sizeof(float), stream);
        spconv_mfma<64><<<cblocks(Kp), blk, 0, stream>>>(t_bf, Wpb, rb_p_in, rb_p_out, P, tilesPerK, wavesPerK, Kp, TPW, resB);
    }
}

// Round 5
// 1468.630 us; speedup vs baseline: 1.1790x; 1.1790x over previous
//
#include <hip/hip_runtime.h>

typedef __attribute__((ext_vector_type(8))) short short8;   // 8 x bf16
typedef __attribute__((ext_vector_type(4))) float f32x4;

__device__ __forceinline__ float lrelu_f(float v) { return v > 0.f ? v : 0.01f * v; }
__device__ __forceinline__ short f2bf(float f) {
    unsigned u = __float_as_uint(f);
    return (short)((u + 0x7FFFu + ((u >> 16) & 1u)) >> 16);    // RNE
}
__device__ __forceinline__ float bf2f(unsigned short h) {
    return __uint_as_float(((unsigned)h) << 16);
}

// fused f32->bf16 converts for x + 5 weight tensors
__global__ __launch_bounds__(256) void convert6(
    const float* __restrict__ x,  short* __restrict__ xb,  int nx,
    const float* __restrict__ W1, short* __restrict__ W1b, int n1,
    const float* __restrict__ W12,short* __restrict__ W12b,int n12,
    const float* __restrict__ W2, short* __restrict__ W2b, int n2,
    const float* __restrict__ W3, short* __restrict__ W3b, int n3,
    const float* __restrict__ Wp, short* __restrict__ Wpb, int np)
{
    const int total = nx + n1 + n12 + n2 + n3 + np;
    for (int i = blockIdx.x * 256 + threadIdx.x; i < total; i += gridDim.x * 256) {
        int j = i;
        if (j < nx)  { xb[j]   = f2bf(x[j]);   continue; } j -= nx;
        if (j < n1)  { W1b[j]  = f2bf(W1[j]);  continue; } j -= n1;
        if (j < n12) { W12b[j] = f2bf(W12[j]); continue; } j -= n12;
        if (j < n2)  { W2b[j]  = f2bf(W2[j]);  continue; } j -= n2;
        if (j < n3)  { W3b[j]  = f2bf(W3[j]);  continue; } j -= n3;
        Wpb[j] = f2bf(Wp[j]);
    }
}

// slot-direct conv: per 16-entry tile, MFMA then write each y-row into its
// output row's slot window (reservation via one returning atomic per entry).
template<int CIN>
__global__ __launch_bounds__(256) void spconv_slot(
    const short* __restrict__ feats,   // [N_in, CIN] bf16
    const short* __restrict__ W,       // [K, CIN, 64] bf16 (global k)
    const int*   __restrict__ iin,
    const int*   __restrict__ iout,
    int P, int kLo, int kHi, int tilesPerK, int wavesPerK, int TPW,
    int* __restrict__ C, int cap, short* __restrict__ yslot)
{
    constexpr int KS = CIN / 32;
    __shared__ short lds[4][16 * 64];
    const int lane = threadIdx.x & 63;
    const int wib  = threadIdx.x >> 6;
    int wid = blockIdx.x * 4 + wib;
    wid = __builtin_amdgcn_readfirstlane(wid);
    const int k = kLo + wid / wavesPerK;
    if (k >= kHi) return;
    const int wslot = wid % wavesPerK;
    int t0 = wslot * TPW;
    if (t0 >= tilesPerK) return;
    const int t1 = (t0 + TPW < tilesPerK) ? t0 + TPW : tilesPerK;
    const int kBase = k * P, kEnd = kBase + P;
    const int col = lane & 15, g = lane >> 4;

    short8 bf[KS][4];
    const short* wk = W + (size_t)k * CIN * 64;
    #pragma unroll
    for (int kk = 0; kk < KS; ++kk)
        #pragma unroll
        for (int ct = 0; ct < 4; ++ct)
            #pragma unroll
            for (int r = 0; r < 8; ++r)
                bf[kk][ct][r] = wk[(size_t)(kk * 32 + g * 8 + r) * 64 + ct * 16 + col];

    short* my = lds[wib];
    const int row = lane >> 2, seg = lane & 3;

    for (int t = t0; t < t1; ++t) {
        const int base = kBase + t * 16;
        // slot reservation early (latency hides under gather+MFMA)
        int rr = -1, pp = cap;
        if (lane < 16) {
            int ee = base + lane;
            if (ee < kEnd) { rr = iout[ee]; pp = atomicAdd(&C[rr], 1); }
        }
        int ein = base + col;
        if (ein >= kEnd) ein = kEnd - 1;
        const int rin = iin[ein];
        short8 af[KS];
        const short* fr = feats + (size_t)rin * CIN + g * 8;
        #pragma unroll
        for (int kk = 0; kk < KS; ++kk)
            af[kk] = *(const short8*)(fr + kk * 32);

        f32x4 acc[4] = {f32x4{0,0,0,0}, f32x4{0,0,0,0}, f32x4{0,0,0,0}, f32x4{0,0,0,0}};
        #pragma unroll
        for (int kk = 0; kk < KS; ++kk)
            #pragma unroll
            for (int ct = 0; ct < 4; ++ct)
                acc[ct] = __builtin_amdgcn_mfma_f32_16x16x32_bf16(af[kk], bf[kk][ct], acc[ct], 0, 0, 0);

        // C row = g*4+j, col = ct*16+col -> LDS row-major [16][64]
        #pragma unroll
        for (int ct = 0; ct < 4; ++ct)
            #pragma unroll
            for (int j = 0; j < 4; ++j)
                my[(g * 4 + j) * 64 + ct * 16 + col] = f2bf(acc[ct][j]);
        short8 v0 = *(const short8*)&my[lane * 16];
        short8 v1 = *(const short8*)&my[lane * 16 + 8];
        const int r2 = __shfl(rr, row);
        const int p2 = __shfl(pp, row);
        if (r2 >= 0 && p2 < cap) {
            short* dst = yslot + ((size_t)r2 * cap + p2) * 64 + seg * 16;
            *(short8*)dst = v0;
            *(short8*)(dst + 8) = v1;
        }
    }
}

// contiguous slot-window reduce: wave = one output row, lane = channel
__global__ __launch_bounds__(256) void reduce_slot(
    const short* __restrict__ yslot, const int* __restrict__ C, int cap,
    float* __restrict__ out, int nRows, int accumulate)
{
    const int lane = threadIdx.x & 63;
    const int r = blockIdx.x * 4 + (threadIdx.x >> 6);
    if (r >= nRows) return;
    int cnt = C[r]; if (cnt > cap) cnt = cap;
    const unsigned short* basep = (const unsigned short*)yslot + (size_t)r * cap * 64 + lane;
    float a0 = 0.f, a1 = 0.f, a2 = 0.f, a3 = 0.f;
    int s = 0;
    for (; s + 4 <= cnt; s += 4) {
        a0 += bf2f(basep[(s + 0) * 64]);
        a1 += bf2f(basep[(s + 1) * 64]);
        a2 += bf2f(basep[(s + 2) * 64]);
        a3 += bf2f(basep[(s + 3) * 64]);
    }
    for (; s < cnt; ++s) a0 += bf2f(basep[s * 64]);
    float v = (a0 + a1) + (a2 + a3);
    float* op = out + (size_t)r * 64 + lane;
    if (accumulate) v += *op;
    *op = v;
}

__global__ __launch_bounds__(256) void bn_stats(
    const float* __restrict__ A, int n, float* __restrict__ stats)
{
    __shared__ float ls[256], lq[256];
    float s = 0.f, q = 0.f;
    const long total = (long)n * 64;
    const long stride = (long)gridDim.x * 256;
    for (long i = (long)blockIdx.x * 256 + threadIdx.x; i < total; i += stride) {
        float v = lrelu_f(A[i]);
        s += v; q += v * v;
    }
    ls[threadIdx.x] = s; lq[threadIdx.x] = q;
    __syncthreads();
    if (threadIdx.x < 64) {
        atomicAdd(&stats[threadIdx.x],
                  ls[threadIdx.x] + ls[threadIdx.x + 64] + ls[threadIdx.x + 128] + ls[threadIdx.x + 192]);
        atomicAdd(&stats[64 + threadIdx.x],
                  lq[threadIdx.x] + lq[threadIdx.x + 64] + lq[threadIdx.x + 128] + lq[threadIdx.x + 192]);
    }
}

__global__ __launch_bounds__(256) void bn_apply(
    const float* __restrict__ A, const float* __restrict__ stats,
    const float* __restrict__ gamma, const float* __restrict__ beta,
    const float* __restrict__ addsrc,
    float* __restrict__ out_f32, short* __restrict__ out_bf, int n)
{
    const int c = threadIdx.x & 63;
    const float inv_n = 1.0f / (float)n;
    const float m   = stats[c] * inv_n;
    const float var = stats[64 + c] * inv_n - m * m;
    const float sc  = rsqrtf(var + 1e-5f) * gamma[c];
    const float bb  = beta[c] - m * sc;
    const long total = (long)n * 64;
    const long stride = (long)gridDim.x * blockDim.x;
    for (long i = (long)blockIdx.x * blockDim.x + threadIdx.x; i < total; i += stride) {
        float r = lrelu_f(A[i]) * sc + bb;
        if (addsrc) r += addsrc[i];
        if (out_f32) out_f32[i] = r;
        if (out_bf)  out_bf[i]  = f2bf(r);
    }
}

// ---------------- CSR fallback (round-3 proven) ----------------
__global__ __launch_bounds__(256) void csr_build(
    const int* __restrict__ iout, int E, int* __restrict__ counts,
    int* __restrict__ slots, int cap)
{
    for (int e = blockIdx.x * 256 + threadIdx.x; e < E; e += gridDim.x * 256) {
        int o = iout[e];
        int pos = atomicAdd(&counts[o], 1);
        if (pos < cap) slots[(size_t)o * cap + pos] = e;
    }
}

template<int CIN>
__global__ __launch_bounds__(256) void spconv_y(
    const short* __restrict__ feats, const short* __restrict__ W,
    const int* __restrict__ iin,
    int P, int kLo, int kHi, int tilesPerK, int wavesPerK, int TPW,
    short* __restrict__ y)
{
    constexpr int KS = CIN / 32;
    __shared__ short lds[4][16 * 64];
    const int lane = threadIdx.x & 63;
    const int wib  = threadIdx.x >> 6;
    int wid = blockIdx.x * 4 + wib;
    wid = __builtin_amdgcn_readfirstlane(wid);
    const int k = kLo + wid / wavesPerK;
    if (k >= kHi) return;
    const int wslot = wid % wavesPerK;
    int t0 = wslot * TPW;
    if (t0 >= tilesPerK) return;
    const int t1 = (t0 + TPW < tilesPerK) ? t0 + TPW : tilesPerK;
    const int kBase = k * P, kEnd = kBase + P;
    const int col = lane & 15, g = lane >> 4;
    short8 bf[KS][4];
    const short* wk = W + (size_t)k * CIN * 64;
    #pragma unroll
    for (int kk = 0; kk < KS; ++kk)
        #pragma unroll
        for (int ct = 0; ct < 4; ++ct)
            #pragma unroll
            for (int r = 0; r < 8; ++r)
                bf[kk][ct][r] = wk[(size_t)(kk * 32 + g * 8 + r) * 64 + ct * 16 + col];
    short* my = lds[wib];
    const size_t eOff = (size_t)kLo * P;
    const int row = lane >> 2, seg = lane & 3;
    for (int t = t0; t < t1; ++t) {
        const int base = kBase + t * 16;
        int ein = base + col;
        if (ein >= kEnd) ein = kEnd - 1;
        const int rin = iin[ein];
        short8 af[KS];
        const short* fr = feats + (size_t)rin * CIN + g * 8;
        #pragma unroll
        for (int kk = 0; kk < KS; ++kk)
            af[kk] = *(const short8*)(fr + kk * 32);
        f32x4 acc[4] = {f32x4{0,0,0,0}, f32x4{0,0,0,0}, f32x4{0,0,0,0}, f32x4{0,0,0,0}};
        #pragma unroll
        for (int kk = 0; kk < KS; ++kk)
            #pragma unroll
            for (int ct = 0; ct < 4; ++ct)
                acc[ct] = __builtin_amdgcn_mfma_f32_16x16x32_bf16(af[kk], bf[kk][ct], acc[ct], 0, 0, 0);
        #pragma unroll
        for (int ct = 0; ct < 4; ++ct)
            #pragma unroll
            for (int j = 0; j < 4; ++j)
                my[(g * 4 + j) * 64 + ct * 16 + col] = f2bf(acc[ct][j]);
        short8 v0 = *(const short8*)&my[lane * 16];
        short8 v1 = *(const short8*)&my[lane * 16 + 8];
        if (base + row < kEnd) {
            short* dst = y + (size_t)(base + row - eOff) * 64 + seg * 16;
            *(short8*)dst = v0;
            *(short8*)(dst + 8) = v1;
        }
    }
}

__global__ __launch_bounds__(256) void reduce_rows(
    const short* __restrict__ y, const int* __restrict__ counts,
    const int* __restrict__ slots, int cap, int eLo, int eHi,
    float* __restrict__ out, int nRows, int accumulate)
{
    const int lane = threadIdx.x & 63;
    const int row = blockIdx.x * 4 + (threadIdx.x >> 6);
    if (row >= nRows) return;
    int cnt = counts[row]; if (cnt > cap) cnt = cap;
    const int* sl = slots + (size_t)row * cap;
    const unsigned short* yu = (const unsigned short*)y;
    float a0 = 0.f, a1 = 0.f, a2 = 0.f, a3 = 0.f;
    int i = 0;
    for (; i + 4 <= cnt; i += 4) {
        int e0 = sl[i], e1 = sl[i+1], e2 = sl[i+2], e3 = sl[i+3];
        if (e0 >= eLo && e0 < eHi) a0 += bf2f(yu[(size_t)(e0 - eLo) * 64 + lane]);
        if (e1 >= eLo && e1 < eHi) a1 += bf2f(yu[(size_t)(e1 - eLo) * 64 + lane]);
        if (e2 >= eLo && e2 < eHi) a2 += bf2f(yu[(size_t)(e2 - eLo) * 64 + lane]);
        if (e3 >= eLo && e3 < eHi) a3 += bf2f(yu[(size_t)(e3 - eLo) * 64 + lane]);
    }
    for (; i < cnt; ++i) {
        int e = sl[i];
        if (e >= eLo && e < eHi) a0 += bf2f(yu[(size_t)(e - eLo) * 64 + lane]);
    }
    float s = (a0 + a1) + (a2 + a3);
    float* op = out + (size_t)row * 64 + lane;
    if (accumulate) s += *op;
    *op = s;
}

// ---------------- atomic fallback ----------------
template<int CIN>
__global__ __launch_bounds__(256) void spconv_mfma(
    const short* __restrict__ feats, const short* __restrict__ W,
    const int* __restrict__ iin, const int* __restrict__ iout,
    int P, int tilesPerK, int wavesPerK, int K, int TPW,
    float* __restrict__ out)
{
    constexpr int KS = CIN / 32;
    const int lane = threadIdx.x & 63;
    int wid = blockIdx.x * 4 + (threadIdx.x >> 6);
    wid = __builtin_amdgcn_readfirstlane(wid);
    const int k = wid / wavesPerK;
    if (k >= K) return;
    const int wslot = wid % wavesPerK;
    int t0 = wslot * TPW;
    if (t0 >= tilesPerK) return;
    const int t1 = (t0 + TPW < tilesPerK) ? t0 + TPW : tilesPerK;
    const int kBase = k * P, kEnd = kBase + P;
    const int col = lane & 15, g = lane >> 4;
    short8 bf[KS][4];
    const short* wk = W + (size_t)k * CIN * 64;
    #pragma unroll
    for (int kk = 0; kk < KS; ++kk)
        #pragma unroll
        for (int ct = 0; ct < 4; ++ct)
            #pragma unroll
            for (int r = 0; r < 8; ++r)
                bf[kk][ct][r] = wk[(size_t)(kk * 32 + g * 8 + r) * 64 + ct * 16 + col];
    for (int t = t0; t < t1; ++t) {
        const int base = kBase + t * 16;
        int ein = base + col;
        if (ein >= kEnd) ein = kEnd - 1;
        const int rin = iin[ein];
        short8 af[KS];
        const short* fr = feats + (size_t)rin * CIN + g * 8;
        #pragma unroll
        for (int kk = 0; kk < KS; ++kk)
            af[kk] = *(const short8*)(fr + kk * 32);
        f32x4 acc[4] = {f32x4{0,0,0,0}, f32x4{0,0,0,0}, f32x4{0,0,0,0}, f32x4{0,0,0,0}};
        #pragma unroll
        for (int kk = 0; kk < KS; ++kk)
            #pragma unroll
            for (int ct = 0; ct < 4; ++ct)
                acc[ct] = __builtin_amdgcn_mfma_f32_16x16x32_bf16(af[kk], bf[kk][ct], acc[ct], 0, 0, 0);
        const int rbase = base + g * 4;
        #pragma unroll
        for (int j = 0; j < 4; ++j) {
            const int er = rbase + j;
            if (er < kEnd) {
                const int rout = iout[er];
                float* op = out + (size_t)rout * 64 + col;
                #pragma unroll
                for (int ct = 0; ct < 4; ++ct)
                    atomicAdd(op + ct * 16, acc[ct][j]);
            }
        }
    }
}

extern "C" void kernel_launch(void* const* d_in, const int* in_sizes, int n_in,
                              void* d_out, int out_size, void* d_ws, size_t ws_size,
                              hipStream_t stream)
{
    const float* x   = (const float*)d_in[0];
    const float* W1  = (const float*)d_in[1];
    const float* W12 = (const float*)d_in[2];
    const float* W2  = (const float*)d_in[3];
    const float* W3  = (const float*)d_in[4];
    const float* Wp  = (const float*)d_in[5];
    const float* g0  = (const float*)d_in[6];
    const float* b0  = (const float*)d_in[7];
    const float* g02 = (const float*)d_in[8];
    const float* b02 = (const float*)d_in[9];
    const float* g1  = (const float*)d_in[10];
    const float* b1  = (const float*)d_in[11];
    const float* g2  = (const float*)d_in[12];
    const float* b2  = (const float*)d_in[13];
    const int* rb_a_in  = (const int*)d_in[14];
    const int* rb_a_out = (const int*)d_in[15];
    const int* rb_b_in  = (const int*)d_in[16];
    const int* rb_b_out = (const int*)d_in[17];
    const int* rb_p_in  = (const int*)d_in[18];
    const int* rb_p_out = (const int*)d_in[19];

    const int N  = in_sizes[0] / 32;
    const int M  = out_size / 64 - N;
    const int Ea = in_sizes[14];
    const int Eb = in_sizes[16];
    const int Ep = in_sizes[18];
    const int Ka = Ea / N, Kp = Ep / N;   // 9, 27
    const int P  = N;

    float* resB = (float*)d_out;
    float* resA = resB + (size_t)M * 64;

    const int CAP_AB = 40, CAP_PFULL = 224, CAP_PCHUNK = 64;

    // ---- workspace layout ----
    size_t off = 0;
    auto take = [&](size_t bytes) { size_t o = off; off += (bytes + 255) & ~(size_t)255; return o; };
    char* base = (char*)d_ws;
    size_t oA   = take((size_t)N * 64 * 4);
    size_t oB   = take((size_t)N * 64 * 4);
    size_t oxb  = take((size_t)N * 32 * 2);
    size_t otb  = take((size_t)N * 64 * 2);
    size_t oW1  = take((size_t)9 * 32 * 64 * 2);
    size_t oW12 = take((size_t)9 * 64 * 64 * 2);
    size_t oW2  = take((size_t)9 * 32 * 64 * 2);
    size_t oW3  = take((size_t)9 * 64 * 64 * 2);
    size_t oWp  = take((size_t)27 * 64 * 64 * 2);
    size_t oCNT = take(((size_t)4 * N + 4 * M + 512) * 4);  // C0..C3 | Cp0..Cp3 | stats[512]
    const size_t oDyn = off;

    float* A     = (float*)(base + oA);
    float* B     = (float*)(base + oB);
    short* x_bf  = (short*)(base + oxb);
    short* t_bf  = (short*)(base + otb);
    short* W1b   = (short*)(base + oW1);
    short* W12b  = (short*)(base + oW12);
    short* W2b   = (short*)(base + oW2);
    short* W3b   = (short*)(base + oW3);
    short* Wpb   = (short*)(base + oWp);
    int*   Cbase = (int*)(base + oCNT);
    int*   C0 = Cbase, *C1 = Cbase + N, *C2 = Cbase + 2 * N, *C3 = Cbase + 3 * N;
    int*   Cp0 = Cbase + 4 * N;
    float* stats = (float*)(Cbase + 4 * N + 4 * M);

    // tier needs
    const size_t yAB    = (size_t)N * CAP_AB * 128;         // 512 MB
    const size_t yPfull = (size_t)M * CAP_PFULL * 128;      // ~717 MB
    const size_t t0need = oDyn + (yPfull > yAB ? yPfull : yAB);
    const size_t t1need = oDyn + yAB;                       // pool chunk cap64 fits in yAB
    // CSR tier layout (round-3)
    size_t oSa = oDyn;
    size_t oSb = oSa + (((size_t)N * CAP_AB * 4 + 255) & ~(size_t)255);
    size_t oSp = oSb + (((size_t)N * CAP_AB * 4 + 255) & ~(size_t)255);
    size_t oYe = oSp + (((size_t)M * CAP_PFULL * 4 + 255) & ~(size_t)255);
    const size_t tCSRneed = oYe + (size_t)Ka * P * 64 * 2;

    dim3 blk(256);
    const int tilesPerK = (P + 15) / 16;
    const int TPW = 4;
    const int wavesPerK = (tilesPerK + TPW - 1) / TPW;
    auto gWaves = [&](int nk) { return dim3((unsigned)((nk * wavesPerK + 3) / 4)); };
    auto gRows  = [](int nr) { return dim3((unsigned)((nr + 3) / 4)); };
    const int nx = N * 32, n1 = 9*32*64, n12 = 9*64*64, n2 = 9*32*64, n3 = 9*64*64, np = 27*64*64;

    convert6<<<1024, blk, 0, stream>>>(x, x_bf, nx, W1, W1b, n1, W12, W12b, n12,
                                       W2, W2b, n2, W3, W3b, n3, Wp, Wpb, np);
    hipMemsetAsync(Cbase, 0, ((size_t)4 * N + 4 * M + 512) * 4, stream);

    if (ws_size >= t1need) {
        short* yslot = (short*)(base + oDyn);
        float* st0 = stats, *st1 = stats + 128, *st2 = stats + 256, *st3 = stats + 384;

        // conv1 (rb_a, 32->64) -> A ; bn -> t_bf
        spconv_slot<32><<<gWaves(Ka), blk, 0, stream>>>(x_bf, W1b, rb_a_in, rb_a_out, P, 0, Ka, tilesPerK, wavesPerK, TPW, C0, CAP_AB, yslot);
        reduce_slot<<<gRows(N), blk, 0, stream>>>(yslot, C0, CAP_AB, A, N, 0);
        bn_stats<<<256, blk, 0, stream>>>(A, N, st0);
        bn_apply<<<512, blk, 0, stream>>>(A, st0, g0, b0, nullptr, nullptr, t_bf, N);

        // conv1_2 (rb_b, 64->64) -> A ; bn -> B (f32)
        spconv_slot<64><<<gWaves(Ka), blk, 0, stream>>>(t_bf, W12b, rb_b_in, rb_b_out, P, 0, Ka, tilesPerK, wavesPerK, TPW, C1, CAP_AB, yslot);
        reduce_slot<<<gRows(N), blk, 0, stream>>>(yslot, C1, CAP_AB, A, N, 0);
        bn_stats<<<256, blk, 0, stream>>>(A, N, st1);
        bn_apply<<<512, blk, 0, stream>>>(A, st1, g02, b02, nullptr, B, nullptr, N);

        // conv2 (rb_b, 32->64) -> A ; bn -> t_bf
        spconv_slot<32><<<gWaves(Ka), blk, 0, stream>>>(x_bf, W2b, rb_b_in, rb_b_out, P, 0, Ka, tilesPerK, wavesPerK, TPW, C2, CAP_AB, yslot);
        reduce_slot<<<gRows(N), blk, 0, stream>>>(yslot, C2, CAP_AB, A, N, 0);
        bn_stats<<<256, blk, 0, stream>>>(A, N, st2);
        bn_apply<<<512, blk, 0, stream>>>(A, st2, g1, b1, nullptr, nullptr, t_bf, N);

        // conv3 (rb_a, 64->64) -> A ; bn + shortcut -> resA + t_bf
        spconv_slot<64><<<gWaves(Ka), blk, 0, stream>>>(t_bf, W3b, rb_a_in, rb_a_out, P, 0, Ka, tilesPerK, wavesPerK, TPW, C3, CAP_AB, yslot);
        reduce_slot<<<gRows(N), blk, 0, stream>>>(yslot, C3, CAP_AB, A, N, 0);
        bn_stats<<<256, blk, 0, stream>>>(A, N, st3);
        bn_apply<<<512, blk, 0, stream>>>(A, st3, g2, b2, B, resA, t_bf, N);

        // pool conv -> resB
        if (ws_size >= t0need) {
            spconv_slot<64><<<gWaves(Kp), blk, 0, stream>>>(t_bf, Wpb, rb_p_in, rb_p_out, P, 0, Kp, tilesPerK, wavesPerK, TPW, Cp0, CAP_PFULL, yslot);
            reduce_slot<<<gRows(M), blk, 0, stream>>>(yslot, Cp0, CAP_PFULL, resB, M, 0);
        } else {
            for (int c = 0; c < 4; ++c) {
                const int kLo = c * Kp / 4, kHi = (c + 1) * Kp / 4;
                int* Cpc = Cp0 + c * M;
                spconv_slot<64><<<gWaves(kHi - kLo), blk, 0, stream>>>(t_bf, Wpb, rb_p_in, rb_p_out, P, kLo, kHi, tilesPerK, wavesPerK, TPW, Cpc, CAP_PCHUNK, yslot);
                reduce_slot<<<gRows(M), blk, 0, stream>>>(yslot, Cpc, CAP_PCHUNK, resB, M, c > 0);
            }
        }
    } else if (ws_size >= tCSRneed) {
        // -------- CSR fallback (round-3) --------
        int* Sa = (int*)(base + oSa);
        int* Sb = (int*)(base + oSb);
        int* Sp = (int*)(base + oSp);
        short* ye = (short*)(base + oYe);
        float* st = stats;

        csr_build<<<2048, blk, 0, stream>>>(rb_a_out, Ea, C0, Sa, CAP_AB);
        csr_build<<<2048, blk, 0, stream>>>(rb_b_out, Eb, C1, Sb, CAP_AB);
        csr_build<<<2048, blk, 0, stream>>>(rb_p_out, Ep, Cp0, Sp, CAP_PFULL);

        spconv_y<32><<<gWaves(Ka), blk, 0, stream>>>(x_bf, W1b, rb_a_in, P, 0, Ka, tilesPerK, wavesPerK, TPW, ye);
        reduce_rows<<<gRows(N), blk, 0, stream>>>(ye, C0, Sa, CAP_AB, 0, Ea, A, N, 0);
        bn_stats<<<256, blk, 0, stream>>>(A, N, st);
        bn_apply<<<512, blk, 0, stream>>>(A, st, g0, b0, nullptr, nullptr, t_bf, N);

        spconv_y<64><<<gWaves(Ka), blk, 0, stream>>>(t_bf, W12b, rb_b_in, P, 0, Ka, tilesPerK, wavesPerK, TPW, ye);
        reduce_rows<<<gRows(N), blk, 0, stream>>>(ye, C1, Sb, CAP_AB, 0, Eb, A, N, 0);
        bn_stats<<<256, blk, 0, stream>>>(A, N, st + 128);
        bn_apply<<<512, blk, 0, stream>>>(A, st + 128, g02, b02, nullptr, B, nullptr, N);

        spconv_y<32><<<gWaves(Ka), blk, 0, stream>>>(x_bf, W2b, rb_b_in, P, 0, Ka, tilesPerK, wavesPerK, TPW, ye);
        reduce_rows<<<gRows(N), blk, 0, stream>>>(ye, C1, Sb, CAP_AB, 0, Eb, A, N, 0);
        bn_stats<<<256, blk, 0, stream>>>(A, N, st + 256);
        bn_apply<<<512, blk, 0, stream>>>(A, st + 256, g1, b1, nullptr, nullptr, t_bf, N);

        spconv_y<64><<<gWaves(Ka), blk, 0, stream>>>(t_bf, W3b, rb_a_in, P, 0, Ka, tilesPerK, wavesPerK, TPW, ye);
        reduce_rows<<<gRows(N), blk, 0, stream>>>(ye, C0, Sa, CAP_AB, 0, Ea, A, N, 0);
        bn_stats<<<256, blk, 0, stream>>>(A, N, st + 384);
        bn_apply<<<512, blk, 0, stream>>>(A, st + 384, g2, b2, B, resA, t_bf, N);

        for (int c = 0; c < 4; ++c) {
            const int kLo = c * Kp / 4, kHi = (c + 1) * Kp / 4;
            spconv_y<64><<<gWaves(kHi - kLo), blk, 0, stream>>>(t_bf, Wpb, rb_p_in, P, kLo, kHi, tilesPerK, wavesPerK, TPW, ye);
            reduce_rows<<<gRows(M), blk, 0, stream>>>(ye, Cp0, Sp, CAP_PFULL, kLo * P, kHi * P, resB, M, c > 0);
        }
    } else {
        // -------- atomic fallback --------
        const int TPW2 = 16;
        const int wPK = (tilesPerK + TPW2 - 1) / TPW2;
        auto cblocks = [&](int K) { return dim3((unsigned)((K * wPK + 3) / 4)); };
        const size_t fbytes = (size_t)N * 64 * sizeof(float);
        float* st = stats;

        hipMemsetAsync(A, 0, fbytes, stream);
        spconv_mfma<32><<<cblocks(Ka), blk, 0, stream>>>(x_bf, W1b, rb_a_in, rb_a_out, P, tilesPerK, wPK, Ka, TPW2, A);
        bn_stats<<<256, blk, 0, stream>>>(A, N, st);
        bn_apply<<<512, blk, 0, stream>>>(A, st, g0, b0, nullptr, nullptr, t_bf, N);

        hipMemsetAsync(A, 0, fbytes, stream);
        spconv_mfma<64><<<cblocks(Ka), blk, 0, stream>>>(t_bf, W12b, rb_b_in, rb_b_out, P, tilesPerK, wPK, Ka, TPW2, A);
        bn_stats<<<256, blk, 0, stream>>>(A, N, st + 128);
        bn_apply<<<512, blk, 0, stream>>>(A, st + 128, g02, b02, nullptr, B, nullptr, N);

        hipMemsetAsync(A, 0, fbytes, stream);
        spconv_mfma<32><<<cblocks(Ka), blk, 0, stream>>>(x_bf, W2b, rb_b_in, rb_b_out, P, tilesPerK, wPK, Ka, TPW2, A);
        bn_stats<<<256, blk, 0, stream>>>(A, N, st + 256);
        bn_apply<<<512, blk, 0, stream>>>(A, st + 256, g1, b1, nullptr, nullptr, t_bf, N);

        hipMemsetAsync(resA, 0, fbytes, stream);
        spconv_mfma<64><<<cblocks(Ka), blk, 0, stream>>>(t_bf, W3b, rb_a_in, rb_a_out, P, tilesPerK, wPK, Ka, TPW2, resA);
        bn_stats<<<256, blk, 0, stream>>>(resA, N, st + 384);
        bn_apply<<<512, blk, 0, stream>>>(resA, st + 384, g2, b2, B, resA, t_bf, N);

        hipMemsetAsync(resB, 0, (size_t)M * 64 * sizeof(float), stream);
        spconv_mfma<64><<<cblocks(Kp), blk, 0, stream>>>(t_bf, Wpb, rb_p_in, rb_p_out, P, tilesPerK, wPK, Kp, TPW2, resB);
    }
}

// Round 6
// 965.890 us; speedup vs baseline: 1.7926x; 1.5205x over previous
//
#include <hip/hip_runtime.h>

typedef __attribute__((ext_vector_type(8))) short short8;   // 8 x bf16
typedef __attribute__((ext_vector_type(4))) float f32x4;

__device__ __forceinline__ float lrelu_f(float v) { return v > 0.f ? v : 0.01f * v; }
__device__ __forceinline__ short f2bf(float f) {
    unsigned u = __float_as_uint(f);
    return (short)((u + 0x7FFFu + ((u >> 16) & 1u)) >> 16);    // RNE
}
__device__ __forceinline__ float bf2f(unsigned short h) {
    return __uint_as_float(((unsigned)h) << 16);
}

// fused f32->bf16 converts for x + 5 weight tensors
__global__ __launch_bounds__(256) void convert6(
    const float* __restrict__ x,  short* __restrict__ xb,  int nx,
    const float* __restrict__ W1, short* __restrict__ W1b, int n1,
    const float* __restrict__ W12,short* __restrict__ W12b,int n12,
    const float* __restrict__ W2, short* __restrict__ W2b, int n2,
    const float* __restrict__ W3, short* __restrict__ W3b, int n3,
    const float* __restrict__ Wp, short* __restrict__ Wpb, int np)
{
    const int total = nx + n1 + n12 + n2 + n3 + np;
    for (int i = blockIdx.x * 256 + threadIdx.x; i < total; i += gridDim.x * 256) {
        int j = i;
        if (j < nx)  { xb[j]   = f2bf(x[j]);   continue; } j -= nx;
        if (j < n1)  { W1b[j]  = f2bf(W1[j]);  continue; } j -= n1;
        if (j < n12) { W12b[j] = f2bf(W12[j]); continue; } j -= n12;
        if (j < n2)  { W2b[j]  = f2bf(W2[j]);  continue; } j -= n2;
        if (j < n3)  { W3b[j]  = f2bf(W3[j]);  continue; } j -= n3;
        Wpb[j] = f2bf(Wp[j]);
    }
}

// slot-direct conv: per 16-entry tile, MFMA, then write each 128B y-row into
// its output row's slot window (pos via one returning atomic per entry).
// Window overflow (pos >= cap) falls back to f32 atomics into outAcc
// (pre-zeroed) -> correct for ANY cap; expected overflow ~1e3 entries.
template<int CIN>
__global__ __launch_bounds__(256) void spconv_slot(
    const short* __restrict__ feats,   // [N_in, CIN] bf16
    const short* __restrict__ W,       // [K, CIN, 64] bf16 (global k)
    const int*   __restrict__ iin,
    const int*   __restrict__ iout,
    int P, int kLo, int kHi, int tilesPerK, int wavesPerK, int TPW,
    int* __restrict__ C, int cap, short* __restrict__ yslot,
    float* __restrict__ outAcc)
{
    constexpr int KS = CIN / 32;
    __shared__ short lds[4][16 * 64];
    const int lane = threadIdx.x & 63;
    const int wib  = threadIdx.x >> 6;
    int wid = blockIdx.x * 4 + wib;
    wid = __builtin_amdgcn_readfirstlane(wid);
    const int k = kLo + wid / wavesPerK;
    if (k >= kHi) return;
    const int wslot = wid % wavesPerK;
    int t0 = wslot * TPW;
    if (t0 >= tilesPerK) return;
    const int t1 = (t0 + TPW < tilesPerK) ? t0 + TPW : tilesPerK;
    const int kBase = k * P, kEnd = kBase + P;
    const int col = lane & 15, g = lane >> 4;

    short8 bf[KS][4];
    const short* wk = W + (size_t)k * CIN * 64;
    #pragma unroll
    for (int kk = 0; kk < KS; ++kk)
        #pragma unroll
        for (int ct = 0; ct < 4; ++ct)
            #pragma unroll
            for (int r = 0; r < 8; ++r)
                bf[kk][ct][r] = wk[(size_t)(kk * 32 + g * 8 + r) * 64 + ct * 16 + col];

    short* my = lds[wib];
    const int row = lane >> 2, seg = lane & 3;

    for (int t = t0; t < t1; ++t) {
        const int base = kBase + t * 16;
        // slot reservation early (latency hides under gather+MFMA)
        int rr = -1, pp = 0;
        if (lane < 16) {
            int ee = base + lane;
            if (ee < kEnd) { rr = iout[ee]; pp = atomicAdd(&C[rr], 1); }
        }
        int ein = base + col;
        if (ein >= kEnd) ein = kEnd - 1;
        const int rin = iin[ein];
        short8 af[KS];
        const short* fr = feats + (size_t)rin * CIN + g * 8;
        #pragma unroll
        for (int kk = 0; kk < KS; ++kk)
            af[kk] = *(const short8*)(fr + kk * 32);

        f32x4 acc[4] = {f32x4{0,0,0,0}, f32x4{0,0,0,0}, f32x4{0,0,0,0}, f32x4{0,0,0,0}};
        #pragma unroll
        for (int kk = 0; kk < KS; ++kk)
            #pragma unroll
            for (int ct = 0; ct < 4; ++ct)
                acc[ct] = __builtin_amdgcn_mfma_f32_16x16x32_bf16(af[kk], bf[kk][ct], acc[ct], 0, 0, 0);

        // C row = g*4+j, col = ct*16+col -> LDS row-major [16][64]
        #pragma unroll
        for (int ct = 0; ct < 4; ++ct)
            #pragma unroll
            for (int j = 0; j < 4; ++j)
                my[(g * 4 + j) * 64 + ct * 16 + col] = f2bf(acc[ct][j]);
        short8 v0 = *(const short8*)&my[lane * 16];
        short8 v1 = *(const short8*)&my[lane * 16 + 8];
        const int r2 = __shfl(rr, row);
        const int p2 = __shfl(pp, row);
        if (r2 >= 0) {
            if (p2 < cap) {
                short* dst = yslot + ((size_t)r2 * cap + p2) * 64 + seg * 16;
                *(short8*)dst = v0;
                *(short8*)(dst + 8) = v1;
            } else {
                float* op = outAcc + (size_t)r2 * 64 + seg * 16;
                #pragma unroll
                for (int j = 0; j < 8; ++j) atomicAdd(op + j,     bf2f((unsigned short)v0[j]));
                #pragma unroll
                for (int j = 0; j < 8; ++j) atomicAdd(op + 8 + j, bf2f((unsigned short)v1[j]));
            }
        }
    }
}

// contiguous slot-window reduce; ALWAYS accumulates into out (pre-zeroed /
// prior chunks / overflow contributions). wave = one output row, lane = channel.
__global__ __launch_bounds__(256) void reduce_slot(
    const short* __restrict__ yslot, const int* __restrict__ C, int cap,
    float* __restrict__ out, int nRows)
{
    const int lane = threadIdx.x & 63;
    const int r = blockIdx.x * 4 + (threadIdx.x >> 6);
    if (r >= nRows) return;
    int cnt = C[r]; if (cnt > cap) cnt = cap;
    const unsigned short* basep = (const unsigned short*)yslot + (size_t)r * cap * 64 + lane;
    float a0 = 0.f, a1 = 0.f, a2 = 0.f, a3 = 0.f;
    int s = 0;
    for (; s + 4 <= cnt; s += 4) {
        a0 += bf2f(basep[(s + 0) * 64]);
        a1 += bf2f(basep[(s + 1) * 64]);
        a2 += bf2f(basep[(s + 2) * 64]);
        a3 += bf2f(basep[(s + 3) * 64]);
    }
    for (; s < cnt; ++s) a0 += bf2f(basep[s * 64]);
    float* op = out + (size_t)r * 64 + lane;
    *op = *op + ((a0 + a1) + (a2 + a3));
}

__global__ __launch_bounds__(256) void bn_stats(
    const float* __restrict__ A, int n, float* __restrict__ stats)
{
    __shared__ float ls[256], lq[256];
    float s = 0.f, q = 0.f;
    const long total = (long)n * 64;
    const long stride = (long)gridDim.x * 256;
    for (long i = (long)blockIdx.x * 256 + threadIdx.x; i < total; i += stride) {
        float v = lrelu_f(A[i]);
        s += v; q += v * v;
    }
    ls[threadIdx.x] = s; lq[threadIdx.x] = q;
    __syncthreads();
    if (threadIdx.x < 64) {
        atomicAdd(&stats[threadIdx.x],
                  ls[threadIdx.x] + ls[threadIdx.x + 64] + ls[threadIdx.x + 128] + ls[threadIdx.x + 192]);
        atomicAdd(&stats[64 + threadIdx.x],
                  lq[threadIdx.x] + lq[threadIdx.x + 64] + lq[threadIdx.x + 128] + lq[threadIdx.x + 192]);
    }
}

// r = bn(lrelu(A)) (+ bf16 addsrc); writes f32 and/or bf16 (either may be null)
__global__ __launch_bounds__(256) void bn_apply(
    const float* __restrict__ A, const float* __restrict__ stats,
    const float* __restrict__ gamma, const float* __restrict__ beta,
    const short* __restrict__ addsrc,
    float* __restrict__ out_f32, short* __restrict__ out_bf, int n)
{
    const int c = threadIdx.x & 63;
    const float inv_n = 1.0f / (float)n;
    const float m   = stats[c] * inv_n;
    const float var = stats[64 + c] * inv_n - m * m;
    const float sc  = rsqrtf(var + 1e-5f) * gamma[c];
    const float bb  = beta[c] - m * sc;
    const long total = (long)n * 64;
    const long stride = (long)gridDim.x * blockDim.x;
    for (long i = (long)blockIdx.x * blockDim.x + threadIdx.x; i < total; i += stride) {
        float r = lrelu_f(A[i]) * sc + bb;
        if (addsrc) r += bf2f(((const unsigned short*)addsrc)[i]);
        if (out_f32) out_f32[i] = r;
        if (out_bf)  out_bf[i]  = f2bf(r);
    }
}

// ---------------- atomic fallback (ws guard) ----------------
template<int CIN>
__global__ __launch_bounds__(256) void spconv_mfma(
    const short* __restrict__ feats, const short* __restrict__ W,
    const int* __restrict__ iin, const int* __restrict__ iout,
    int P, int tilesPerK, int wavesPerK, int K, int TPW,
    float* __restrict__ out)
{
    constexpr int KS = CIN / 32;
    const int lane = threadIdx.x & 63;
    int wid = blockIdx.x * 4 + (threadIdx.x >> 6);
    wid = __builtin_amdgcn_readfirstlane(wid);
    const int k = wid / wavesPerK;
    if (k >= K) return;
    const int wslot = wid % wavesPerK;
    int t0 = wslot * TPW;
    if (t0 >= tilesPerK) return;
    const int t1 = (t0 + TPW < tilesPerK) ? t0 + TPW : tilesPerK;
    const int kBase = k * P, kEnd = kBase + P;
    const int col = lane & 15, g = lane >> 4;
    short8 bf[KS][4];
    const short* wk = W + (size_t)k * CIN * 64;
    #pragma unroll
    for (int kk = 0; kk < KS; ++kk)
        #pragma unroll
        for (int ct = 0; ct < 4; ++ct)
            #pragma unroll
            for (int r = 0; r < 8; ++r)
                bf[kk][ct][r] = wk[(size_t)(kk * 32 + g * 8 + r) * 64 + ct * 16 + col];
    for (int t = t0; t < t1; ++t) {
        const int base = kBase + t * 16;
        int ein = base + col;
        if (ein >= kEnd) ein = kEnd - 1;
        const int rin = iin[ein];
        short8 af[KS];
        const short* fr = feats + (size_t)rin * CIN + g * 8;
        #pragma unroll
        for (int kk = 0; kk < KS; ++kk)
            af[kk] = *(const short8*)(fr + kk * 32);
        f32x4 acc[4] = {f32x4{0,0,0,0}, f32x4{0,0,0,0}, f32x4{0,0,0,0}, f32x4{0,0,0,0}};
        #pragma unroll
        for (int kk = 0; kk < KS; ++kk)
            #pragma unroll
            for (int ct = 0; ct < 4; ++ct)
                acc[ct] = __builtin_amdgcn_mfma_f32_16x16x32_bf16(af[kk], bf[kk][ct], acc[ct], 0, 0, 0);
        const int rbase = base + g * 4;
        #pragma unroll
        for (int j = 0; j < 4; ++j) {
            const int er = rbase + j;
            if (er < kEnd) {
                const int rout = iout[er];
                float* op = out + (size_t)rout * 64 + col;
                #pragma unroll
                for (int ct = 0; ct < 4; ++ct)
                    atomicAdd(op + ct * 16, acc[ct][j]);
            }
        }
    }
}

extern "C" void kernel_launch(void* const* d_in, const int* in_sizes, int n_in,
                              void* d_out, int out_size, void* d_ws, size_t ws_size,
                              hipStream_t stream)
{
    const float* x   = (const float*)d_in[0];
    const float* W1  = (const float*)d_in[1];
    const float* W12 = (const float*)d_in[2];
    const float* W2  = (const float*)d_in[3];
    const float* W3  = (const float*)d_in[4];
    const float* Wp  = (const float*)d_in[5];
    const float* g0  = (const float*)d_in[6];
    const float* b0  = (const float*)d_in[7];
    const float* g02 = (const float*)d_in[8];
    const float* b02 = (const float*)d_in[9];
    const float* g1  = (const float*)d_in[10];
    const float* b1  = (const float*)d_in[11];
    const float* g2  = (const float*)d_in[12];
    const float* b2  = (const float*)d_in[13];
    const int* rb_a_in  = (const int*)d_in[14];
    const int* rb_a_out = (const int*)d_in[15];
    const int* rb_b_in  = (const int*)d_in[16];
    const int* rb_b_out = (const int*)d_in[17];
    const int* rb_p_in  = (const int*)d_in[18];
    const int* rb_p_out = (const int*)d_in[19];

    const int N  = in_sizes[0] / 32;
    const int M  = out_size / 64 - N;
    const int Ea = in_sizes[14];
    const int Ep = in_sizes[18];
    const int Ka = Ea / N, Kp = Ep / N;   // 9, 27
    const int P  = N;

    float* resB = (float*)d_out;
    float* resA = resB + (size_t)M * 64;

    // ---- workspace layout ----
    size_t off = 0;
    auto take = [&](size_t bytes) { size_t o = off; off += (bytes + 255) & ~(size_t)255; return o; };
    char* base = (char*)d_ws;
    size_t oA   = take((size_t)N * 64 * 4);       // f32 accumulator (+overflow target)
    size_t oBbf = take((size_t)N * 64 * 2);       // bf16 shortcut
    size_t oxb  = take((size_t)N * 32 * 2);
    size_t otb  = take((size_t)N * 64 * 2);
    size_t oW1  = take((size_t)9 * 32 * 64 * 2);
    size_t oW12 = take((size_t)9 * 64 * 64 * 2);
    size_t oW2  = take((size_t)9 * 32 * 64 * 2);
    size_t oW3  = take((size_t)9 * 64 * 64 * 2);
    size_t oWp  = take((size_t)27 * 64 * 64 * 2);
    size_t oCNT = take(((size_t)4 * N + 4 * M + 512) * 4);  // C0..C3 | Cp0..Cp3 | stats[512]
    const size_t oDyn = off;

    float* A     = (float*)(base + oA);
    short* B_bf  = (short*)(base + oBbf);
    short* x_bf  = (short*)(base + oxb);
    short* t_bf  = (short*)(base + otb);
    short* W1b   = (short*)(base + oW1);
    short* W12b  = (short*)(base + oW12);
    short* W2b   = (short*)(base + oW2);
    short* W3b   = (short*)(base + oW3);
    short* Wpb   = (short*)(base + oWp);
    int*   Cbase = (int*)(base + oCNT);
    int*   C0 = Cbase, *C1 = Cbase + N, *C2 = Cbase + 2 * N, *C3 = Cbase + 3 * N;
    int*   Cp0 = Cbase + 4 * N;
    float* stats = (float*)(Cbase + 4 * N + 4 * M);
    short* yslot = (short*)(base + oDyn);

    // dynamic caps from available window space (overflow path keeps ANY cap correct)
    const size_t avail = (ws_size > oDyn) ? (ws_size - oDyn) : 0;
    int capAB = (int)((avail / ((size_t)N * 128)) < 24 ? (avail / ((size_t)N * 128)) : 24);
    int capP  = (int)((avail / ((size_t)M * 128)) < 48 ? (avail / ((size_t)M * 128)) : 48);

    dim3 blk(256);
    const int tilesPerK = (P + 15) / 16;
    const int TPW = 4;
    const int wavesPerK = (tilesPerK + TPW - 1) / TPW;
    auto gWaves = [&](int nk) { return dim3((unsigned)((nk * wavesPerK + 3) / 4)); };
    auto gRows  = [](int nr) { return dim3((unsigned)((nr + 3) / 4)); };
    const int nx = N * 32, n1 = 9*32*64, n12 = 9*64*64, n2 = 9*32*64, n3 = 9*64*64, np = 27*64*64;
    const size_t fbytes = (size_t)N * 64 * sizeof(float);

    convert6<<<1024, blk, 0, stream>>>(x, x_bf, nx, W1, W1b, n1, W12, W12b, n12,
                                       W2, W2b, n2, W3, W3b, n3, Wp, Wpb, np);
    hipMemsetAsync(Cbase, 0, ((size_t)4 * N + 4 * M + 512) * 4, stream);

    if (capAB >= 8 && capP >= 24) {
        float* st0 = stats, *st1 = stats + 128, *st2 = stats + 256, *st3 = stats + 384;

        // conv1 (rb_a, 32->64) -> A ; bn -> t_bf
        hipMemsetAsync(A, 0, fbytes, stream);
        spconv_slot<32><<<gWaves(Ka), blk, 0, stream>>>(x_bf, W1b, rb_a_in, rb_a_out, P, 0, Ka, tilesPerK, wavesPerK, TPW, C0, capAB, yslot, A);
        reduce_slot<<<gRows(N), blk, 0, stream>>>(yslot, C0, capAB, A, N);
        bn_stats<<<256, blk, 0, stream>>>(A, N, st0);
        bn_apply<<<512, blk, 0, stream>>>(A, st0, g0, b0, nullptr, nullptr, t_bf, N);

        // conv1_2 (rb_b, 64->64) -> A ; bn -> B_bf (bf16 shortcut)
        hipMemsetAsync(A, 0, fbytes, stream);
        spconv_slot<64><<<gWaves(Ka), blk, 0, stream>>>(t_bf, W12b, rb_b_in, rb_b_out, P, 0, Ka, tilesPerK, wavesPerK, TPW, C1, capAB, yslot, A);
        reduce_slot<<<gRows(N), blk, 0, stream>>>(yslot, C1, capAB, A, N);
        bn_stats<<<256, blk, 0, stream>>>(A, N, st1);
        bn_apply<<<512, blk, 0, stream>>>(A, st1, g02, b02, nullptr, nullptr, B_bf, N);

        // conv2 (rb_b, 32->64) -> A ; bn -> t_bf
        hipMemsetAsync(A, 0, fbytes, stream);
        spconv_slot<32><<<gWaves(Ka), blk, 0, stream>>>(x_bf, W2b, rb_b_in, rb_b_out, P, 0, Ka, tilesPerK, wavesPerK, TPW, C2, capAB, yslot, A);
        reduce_slot<<<gRows(N), blk, 0, stream>>>(yslot, C2, capAB, A, N);
        bn_stats<<<256, blk, 0, stream>>>(A, N, st2);
        bn_apply<<<512, blk, 0, stream>>>(A, st2, g1, b1, nullptr, nullptr, t_bf, N);

        // conv3 (rb_a, 64->64) -> A ; bn + shortcut -> resA (f32) + t_bf (bf16)
        hipMemsetAsync(A, 0, fbytes, stream);
        spconv_slot<64><<<gWaves(Ka), blk, 0, stream>>>(t_bf, W3b, rb_a_in, rb_a_out, P, 0, Ka, tilesPerK, wavesPerK, TPW, C3, capAB, yslot, A);
        reduce_slot<<<gRows(N), blk, 0, stream>>>(yslot, C3, capAB, A, N);
        bn_stats<<<256, blk, 0, stream>>>(A, N, st3);
        bn_apply<<<512, blk, 0, stream>>>(A, st3, g2, b2, B_bf, resA, t_bf, N);

        // pool conv (rb_p, 64->64), 4 k-chunks reusing the y window -> resB
        hipMemsetAsync(resB, 0, (size_t)M * 64 * sizeof(float), stream);
        const int kc[5] = {0, 7, 14, 21, Kp};
        for (int c = 0; c < 4; ++c) {
            const int kLo = kc[c], kHi = kc[c + 1];
            int* Cpc = Cp0 + c * M;
            spconv_slot<64><<<gWaves(kHi - kLo), blk, 0, stream>>>(t_bf, Wpb, rb_p_in, rb_p_out, P, kLo, kHi, tilesPerK, wavesPerK, TPW, Cpc, capP, yslot, resB);
            reduce_slot<<<gRows(M), blk, 0, stream>>>(yslot, Cpc, capP, resB, M);
        }
    } else {
        // -------- atomic fallback --------
        const int TPW2 = 16;
        const int wPK = (tilesPerK + TPW2 - 1) / TPW2;
        auto cblocks = [&](int K) { return dim3((unsigned)((K * wPK + 3) / 4)); };
        float* st = stats;

        hipMemsetAsync(A, 0, fbytes, stream);
        spconv_mfma<32><<<cblocks(Ka), blk, 0, stream>>>(x_bf, W1b, rb_a_in, rb_a_out, P, tilesPerK, wPK, Ka, TPW2, A);
        bn_stats<<<256, blk, 0, stream>>>(A, N, st);
        bn_apply<<<512, blk, 0, stream>>>(A, st, g0, b0, nullptr, nullptr, t_bf, N);

        hipMemsetAsync(A, 0, fbytes, stream);
        spconv_mfma<64><<<cblocks(Ka), blk, 0, stream>>>(t_bf, W12b, rb_b_in, rb_b_out, P, tilesPerK, wPK, Ka, TPW2, A);
        bn_stats<<<256, blk, 0, stream>>>(A, N, st + 128);
        bn_apply<<<512, blk, 0, stream>>>(A, st + 128, g02, b02, nullptr, nullptr, B_bf, N);

        hipMemsetAsync(A, 0, fbytes, stream);
        spconv_mfma<32><<<cblocks(Ka), blk, 0, stream>>>(x_bf, W2b, rb_b_in, rb_b_out, P, tilesPerK, wPK, Ka, TPW2, A);
        bn_stats<<<256, blk, 0, stream>>>(A, N, st + 256);
        bn_apply<<<512, blk, 0, stream>>>(A, st + 256, g1, b1, nullptr, nullptr, t_bf, N);

        hipMemsetAsync(resA, 0, fbytes, stream);
        spconv_mfma<64><<<cblocks(Ka), blk, 0, stream>>>(t_bf, W3b, rb_a_in, rb_a_out, P, tilesPerK, wPK, Ka, TPW2, resA);
        bn_stats<<<256, blk, 0, stream>>>(resA, N, st + 384);
        bn_apply<<<512, blk, 0, stream>>>(resA, st + 384, g2, b2, B_bf, resA, t_bf, N);

        hipMemsetAsync(resB, 0, (size_t)M * 64 * sizeof(float), stream);
        spconv_mfma<64><<<cblocks(Kp), blk, 0, stream>>>(t_bf, Wpb, rb_p_in, rb_p_out, P, tilesPerK, wPK, Kp, TPW2, resB);
    }
}